// Round 1
// baseline (819.907 us; speedup 1.0000x reference)
//
#include <hip/hip_runtime.h>

// Attention with policy-softmax, MI355X (gfx950).
// Shapes: B=16, N=1024, C=768, H=12, hd=64.
// Pipeline: cvt f32->f16 -> QKV GEMM (MFMA f16) -> fused policy-softmax attention -> proj GEMM.
// All matmuls use v_mfma_f32_16x16x32_f16 (fp32 accumulate).
// Workspace layout (f16 elements):
//   x_h     [16384*768]   (reused later for attn output)
//   wqkv_h  [2304*768]
//   wproj_h [768*768]
//   q_h     [B,H,N,hd]
//   k_h     [B,H,N,hd]
//   vt_h    [B,H,hd,N]    (V transposed so PV B-frags are contiguous loads)
// Total ~105 MB.

#define NB 16
#define NN 1024
#define NC 768
#define NH 12
#define HD 64
#define NM (NB*NN)      // 16384
#define QKVC (3*NC)     // 2304

typedef _Float16 f16;
typedef _Float16 f16x8 __attribute__((ext_vector_type(8)));
typedef _Float16 f16x4 __attribute__((ext_vector_type(4)));
typedef float f32x4 __attribute__((ext_vector_type(4)));

__device__ inline f16x8 as_f16x8(uint4 u){
  union { uint4 u; f16x8 h; } v; v.u = u; return v.h;
}

// ---------------- fp32 -> f16 convert (vectorized x4) ----------------
__global__ void cvt_f32_f16(const float* __restrict__ in, f16* __restrict__ out, int n4){
  int i = blockIdx.x*blockDim.x + threadIdx.x;
  if (i < n4){
    float4 v = ((const float4*)in)[i];
    f16x4 h; h[0]=(f16)v.x; h[1]=(f16)v.y; h[2]=(f16)v.z; h[3]=(f16)v.w;
    ((f16x4*)out)[i] = h;
  }
}

// ---------------- QKV GEMM: [16384,768] x [2304,768]^T -----------------
// 64x64 tile, 256 threads = 4 waves; wave w computes rows [w*16,w*16+16) x 64 cols.
// MFMA 16x16x32_f16 layouts:
//   A: lane l holds A[m=l&15][k=(l>>4)*8+j], j=0..7 (contiguous k)
//   B: lane l holds B[k=(l>>4)*8+j][n=l&15]
//   D: lane l holds D[row=(l>>4)*4+i][col=l&15], i=0..3
__launch_bounds__(256)
__global__ void gemm_qkv(const f16* __restrict__ X, const f16* __restrict__ W,
                         f16* __restrict__ Q, f16* __restrict__ K, f16* __restrict__ VT){
  __shared__ f16 sA[64][40];   // stride 40 halves = 80B: 16B-aligned rows, 2-way banks (free)
  __shared__ f16 sB[64][40];
  const int R0 = blockIdx.y*64, C0 = blockIdx.x*64;
  const int t = threadIdx.x;
  const int w = t >> 6, l = t & 63, quad = l >> 4, lr = l & 15;
  const int lrow = t >> 2, lk = (t & 3)*8;
  f32x4 acc[4] = {};
  for (int bk = 0; bk < NC; bk += 32){
    uint4 a = *(const uint4*)(X + (size_t)(R0 + lrow)*NC + bk + lk);
    uint4 b = *(const uint4*)(W + (size_t)(C0 + lrow)*NC + bk + lk);
    __syncthreads();
    *(uint4*)&sA[lrow][lk] = a;
    *(uint4*)&sB[lrow][lk] = b;
    __syncthreads();
    f16x8 af = as_f16x8(*(const uint4*)&sA[w*16 + lr][quad*8]);
#pragma unroll
    for (int nt = 0; nt < 4; nt++){
      f16x8 bf = as_f16x8(*(const uint4*)&sB[nt*16 + lr][quad*8]);
      acc[nt] = __builtin_amdgcn_mfma_f32_16x16x32_f16(af, bf, acc[nt], 0, 0, 0);
    }
  }
  // scatter into Q / K / V^T.  col -> (type, h, d): 2304 = 3*12*64
#pragma unroll
  for (int nt = 0; nt < 4; nt++){
    int colg = C0 + nt*16 + lr;
    int type = colg / NC;             // uniform per nt-tile (16 | 768)
    int rem  = colg - type*NC;
    int hh = rem >> 6, d = rem & 63;
#pragma unroll
    for (int i = 0; i < 4; i++){
      int row = R0 + w*16 + quad*4 + i;
      int bb = row >> 10, np = row & 1023;
      int bh = bb*NH + hh;
      f16 v = (f16)acc[nt][i];
      if (type == 0)      Q[(bh << 16) + (np << 6) + d] = v;
      else if (type == 1) K[(bh << 16) + (np << 6) + d] = v;
      else                VT[(bh << 16) + (d << 10) + np] = v;
    }
  }
}

// ---------------- fused policy-softmax attention ----------------
// 1 block = (b, h, 16 q-rows), 256 threads = 4 waves.
// Phase 1: S[16][1024] = scale * Q Kt  (K direct from global, 16B/lane)
// Phase 2: policy softmax in LDS (exact reference semantics)
// Phase 3: O = P V with waves splitting key range; LDS partial reduce.
__launch_bounds__(256)
__global__ void attn_kernel(const f16* __restrict__ Q, const f16* __restrict__ K,
                            const f16* __restrict__ VT, const float* __restrict__ policy,
                            f16* __restrict__ O){
  __shared__ float sS[16][1028];    // 65792 B (stride 1028: 16B-aligned, 2-way banks)
  __shared__ f16 sQ[16][80];
  __shared__ float sPol[1024];
  __shared__ float sRed[16][16];
  __shared__ float sMax[16];
  __shared__ float sSum[16];

  const int blk = blockIdx.x;
  const int b = blk / (NH*64);
  const int rem = blk % (NH*64);
  const int h = rem >> 6;
  const int qt = rem & 63;
  const int bh = b*NH + h;
  const size_t base = (size_t)bh << 16;   // *N*hd

  const int t = threadIdx.x;
  const int w = t >> 6, l = t & 63, quad = l >> 4, lr = l & 15;

  { // load Q tile (16x64) and policy row
    int r = t >> 4, k0 = (t & 15)*4;
    *(uint2*)&sQ[r][k0] = *(const uint2*)(Q + base + (size_t)(qt*16 + r)*HD + k0);
    *(float4*)&sPol[t*4] = *(const float4*)(policy + b*NN + t*4);
  }
  __syncthreads();

  // ---- S = scale * Q K^T : wave w covers key cols [w*256, w*256+256)
#pragma unroll
  for (int ct = 0; ct < 16; ct++){
    int col0 = w*256 + ct*16;
    f32x4 acc = {};
#pragma unroll
    for (int kk = 0; kk < HD; kk += 32){
      f16x8 af = as_f16x8(*(const uint4*)&sQ[lr][kk + quad*8]);
      f16x8 bf = as_f16x8(*(const uint4*)(K + base + (size_t)(col0 + lr)*HD + kk + quad*8));
      acc = __builtin_amdgcn_mfma_f32_16x16x32_f16(af, bf, acc, 0, 0, 0);
    }
#pragma unroll
    for (int i = 0; i < 4; i++)
      sS[quad*4 + i][col0 + lr] = acc[i] * 0.125f;   // hd^-0.5
  }
  __syncthreads();

  // ---- policy softmax: a = exp(s - max)*pol; p = (a + eps/N)/(sum + eps)
  {
    int r = t >> 4, s = t & 15;
    int qg = qt*16 + r;                 // global query index (diagonal)
    float m = -3.4e38f;
    for (int c = s; c < NN; c += 16) m = fmaxf(m, sS[r][c]);
    sRed[r][s] = m;
    __syncthreads();
    if (t < 16){
      float mm = sRed[t][0];
      for (int j = 1; j < 16; j++) mm = fmaxf(mm, sRed[t][j]);
      sMax[t] = mm;
    }
    __syncthreads();
    float rmax = sMax[r];
    float sum = 0.f;
    for (int c = s; c < NN; c += 16){
      float pol = (c == qg) ? 1.0f : sPol[c];
      float a = __expf(sS[r][c] - rmax) * pol;
      sS[r][c] = a;
      sum += a;
    }
    sRed[r][s] = sum;
    __syncthreads();
    if (t < 16){
      float ss = 0.f;
      for (int j = 0; j < 16; j++) ss += sRed[t][j];
      sSum[t] = ss;
    }
    __syncthreads();
    float inv = 1.0f / (sSum[r] + 1e-6f);
    const float addc = 1e-6f / 1024.0f;
    for (int c = s; c < NN; c += 16)
      sS[r][c] = (sS[r][c] + addc) * inv;
  }
  __syncthreads();

  // ---- O = P V : wave w handles keys [w*256, w*256+256), all 64 dims
  f32x4 acc[4] = {};
#pragma unroll
  for (int s8 = 0; s8 < 8; s8++){
    int kb = w*256 + s8*32;
    const float* prow = &sS[lr][kb + quad*8];
    f16x8 af;
#pragma unroll
    for (int j = 0; j < 8; j++) af[j] = (f16)prow[j];
#pragma unroll
    for (int nt = 0; nt < 4; nt++){
      f16x8 bf = as_f16x8(*(const uint4*)(VT + base + (size_t)(nt*16 + lr)*NN + kb + quad*8));
      acc[nt] = __builtin_amdgcn_mfma_f32_16x16x32_f16(af, bf, acc[nt], 0, 0, 0);
    }
  }
  __syncthreads();           // all P reads done before overwriting sS
  float* sPart = &sS[0][0];  // reuse as [4][16][64] partials
#pragma unroll
  for (int nt = 0; nt < 4; nt++)
#pragma unroll
    for (int i = 0; i < 4; i++)
      sPart[w*1024 + (quad*4 + i)*64 + nt*16 + lr] = acc[nt][i];
  __syncthreads();
  { // reduce 4 wave-partials, write [B,N,C] f16
    int o0 = t*4;
    int r = o0 >> 6, d = o0 & 63;
    f16x4 v;
#pragma unroll
    for (int j = 0; j < 4; j++){
      float s = sPart[o0 + j] + sPart[1024 + o0 + j] + sPart[2048 + o0 + j] + sPart[3072 + o0 + j];
      v[j] = (f16)s;
    }
    *(f16x4*)(O + (size_t)(b*NN + qt*16 + r)*NC + h*HD + d) = v;
  }
}

// ---------------- proj GEMM: [16384,768] x [768,768]^T + bias -> fp32 ----------------
__launch_bounds__(256)
__global__ void gemm_proj(const f16* __restrict__ A, const f16* __restrict__ W,
                          const float* __restrict__ bias, float* __restrict__ out){
  __shared__ f16 sA[64][40];
  __shared__ f16 sB[64][40];
  const int R0 = blockIdx.y*64, C0 = blockIdx.x*64;
  const int t = threadIdx.x;
  const int w = t >> 6, l = t & 63, quad = l >> 4, lr = l & 15;
  const int lrow = t >> 2, lk = (t & 3)*8;
  f32x4 acc[4] = {};
  for (int bk = 0; bk < NC; bk += 32){
    uint4 a = *(const uint4*)(A + (size_t)(R0 + lrow)*NC + bk + lk);
    uint4 b = *(const uint4*)(W + (size_t)(C0 + lrow)*NC + bk + lk);
    __syncthreads();
    *(uint4*)&sA[lrow][lk] = a;
    *(uint4*)&sB[lrow][lk] = b;
    __syncthreads();
    f16x8 af = as_f16x8(*(const uint4*)&sA[w*16 + lr][quad*8]);
#pragma unroll
    for (int nt = 0; nt < 4; nt++){
      f16x8 bf = as_f16x8(*(const uint4*)&sB[nt*16 + lr][quad*8]);
      acc[nt] = __builtin_amdgcn_mfma_f32_16x16x32_f16(af, bf, acc[nt], 0, 0, 0);
    }
  }
#pragma unroll
  for (int nt = 0; nt < 4; nt++){
    int colg = C0 + nt*16 + lr;
    float bv = bias[colg];
#pragma unroll
    for (int i = 0; i < 4; i++){
      int row = R0 + w*16 + quad*4 + i;
      out[(size_t)row*NC + colg] = acc[nt][i] + bv;
    }
  }
}

extern "C" void kernel_launch(void* const* d_in, const int* in_sizes, int n_in,
                              void* d_out, int out_size, void* d_ws, size_t ws_size,
                              hipStream_t stream) {
  const float* x      = (const float*)d_in[0];
  const float* policy = (const float*)d_in[1];
  const float* w_qkv  = (const float*)d_in[2];
  const float* w_proj = (const float*)d_in[3];
  const float* b_proj = (const float*)d_in[4];
  float* out = (float*)d_out;

  f16* x_h     = (f16*)d_ws;
  f16* wqkv_h  = x_h + (size_t)NM*NC;          // 12582912
  f16* wproj_h = wqkv_h + (size_t)QKVC*NC;     // +1769472
  f16* q_h     = wproj_h + (size_t)NC*NC;      // +589824
  f16* k_h     = q_h + (size_t)NM*NC;
  f16* vt_h    = k_h + (size_t)NM*NC;
  f16* attn_h  = x_h;                          // x dead after gemm_qkv -> reuse

  // converts
  cvt_f32_f16<<<(NM*NC/4 + 255)/256, 256, 0, stream>>>(x, x_h, NM*NC/4);
  cvt_f32_f16<<<(QKVC*NC/4 + 255)/256, 256, 0, stream>>>(w_qkv, wqkv_h, QKVC*NC/4);
  cvt_f32_f16<<<(NC*NC/4 + 255)/256, 256, 0, stream>>>(w_proj, wproj_h, NC*NC/4);

  // qkv = x @ w_qkv^T  (scatter into q/k/vt)
  gemm_qkv<<<dim3(QKVC/64, NM/64), 256, 0, stream>>>(x_h, wqkv_h, q_h, k_h, vt_h);

  // fused attention
  attn_kernel<<<dim3(NB*NH*(NN/16)), 256, 0, stream>>>(q_h, k_h, vt_h, policy, attn_h);

  // out = attn @ w_proj^T + b
  gemm_proj<<<dim3(NC/64, NM/64), 256, 0, stream>>>(attn_h, wproj_h, b_proj, out);
}

// Round 2
// 708.408 us; speedup vs baseline: 1.1574x; 1.1574x over previous
//
#include <hip/hip_runtime.h>

// Attention with policy-softmax, MI355X (gfx950).
// Shapes: B=16, N=1024, C=768, H=12, hd=64.
// R2: attention restructured — S^T = K·Q^T kept in registers (64 VGPR/lane),
// softmax via in-lane reduce + shfl_xor + tiny LDS; P -> LDS as f16 with
// ds_write_b64, PV A-frags via ds_read_b128. LDS 73.7KB -> 36.1KB.

#define NB 16
#define NN 1024
#define NC 768
#define NH 12
#define HD 64
#define NM (NB*NN)      // 16384
#define QKVC (3*NC)     // 2304

typedef _Float16 f16;
typedef _Float16 f16x8 __attribute__((ext_vector_type(8)));
typedef _Float16 f16x4 __attribute__((ext_vector_type(4)));
typedef float f32x4 __attribute__((ext_vector_type(4)));

__device__ inline f16x8 as_f16x8(uint4 u){
  union { uint4 u; f16x8 h; } v; v.u = u; return v.h;
}

// ---------------- fp32 -> f16 convert (vectorized x4) ----------------
__global__ void cvt_f32_f16(const float* __restrict__ in, f16* __restrict__ out, int n4){
  int i = blockIdx.x*blockDim.x + threadIdx.x;
  if (i < n4){
    float4 v = ((const float4*)in)[i];
    f16x4 h; h[0]=(f16)v.x; h[1]=(f16)v.y; h[2]=(f16)v.z; h[3]=(f16)v.w;
    ((f16x4*)out)[i] = h;
  }
}

// ---------------- QKV GEMM: [16384,768] x [2304,768]^T -----------------
__launch_bounds__(256)
__global__ void gemm_qkv(const f16* __restrict__ X, const f16* __restrict__ W,
                         f16* __restrict__ Q, f16* __restrict__ K, f16* __restrict__ VT){
  __shared__ f16 sA[64][40];
  __shared__ f16 sB[64][40];
  const int R0 = blockIdx.y*64, C0 = blockIdx.x*64;
  const int t = threadIdx.x;
  const int w = t >> 6, l = t & 63, quad = l >> 4, lr = l & 15;
  const int lrow = t >> 2, lk = (t & 3)*8;
  f32x4 acc[4] = {};
  for (int bk = 0; bk < NC; bk += 32){
    uint4 a = *(const uint4*)(X + (size_t)(R0 + lrow)*NC + bk + lk);
    uint4 b = *(const uint4*)(W + (size_t)(C0 + lrow)*NC + bk + lk);
    __syncthreads();
    *(uint4*)&sA[lrow][lk] = a;
    *(uint4*)&sB[lrow][lk] = b;
    __syncthreads();
    f16x8 af = as_f16x8(*(const uint4*)&sA[w*16 + lr][quad*8]);
#pragma unroll
    for (int nt = 0; nt < 4; nt++){
      f16x8 bf = as_f16x8(*(const uint4*)&sB[nt*16 + lr][quad*8]);
      acc[nt] = __builtin_amdgcn_mfma_f32_16x16x32_f16(af, bf, acc[nt], 0, 0, 0);
    }
  }
#pragma unroll
  for (int nt = 0; nt < 4; nt++){
    int colg = C0 + nt*16 + lr;
    int type = colg / NC;
    int rem  = colg - type*NC;
    int hh = rem >> 6, d = rem & 63;
#pragma unroll
    for (int i = 0; i < 4; i++){
      int row = R0 + w*16 + quad*4 + i;
      int bb = row >> 10, np = row & 1023;
      int bh = bb*NH + hh;
      f16 v = (f16)acc[nt][i];
      if (type == 0)      Q[(bh << 16) + (np << 6) + d] = v;
      else if (type == 1) K[(bh << 16) + (np << 6) + d] = v;
      else                VT[(bh << 16) + (d << 10) + np] = v;
    }
  }
}

// ---------------- fused policy-softmax attention ----------------
// 1 block = (b, h, 16 q-rows), 256 threads = 4 waves; wave w owns keys [w*256, w*256+256).
// Phase 1: S^T = K Q^T via MFMA -> lane(quad,lr) holds keys {16ct+quad*4+i} for query lr (regs).
// Phase 2: softmax entirely in registers (in-lane + shfl_xor(16,32) + 4-wave LDS combine).
// Phase 3: P (f16, LDS, b64 writes / b128 reads) x V^T -> partial-reduce across waves.
#define SP_STRIDE 1032   // f16; 16B-aligned rows (1032*2 % 16 == 0)
__launch_bounds__(256, 4)
__global__ void attn_kernel(const f16* __restrict__ Q, const f16* __restrict__ K,
                            const f16* __restrict__ VT, const float* __restrict__ policy,
                            f16* __restrict__ O){
  __shared__ __align__(16) char smem[16*SP_STRIDE*2 + 16*80*2 + 2*64*4];
  f16 (*sP)[SP_STRIDE] = (f16(*)[SP_STRIDE])smem;            // 33024 B (P, later f32 partials)
  f16 (*sQ)[80]        = (f16(*)[80])(smem + 16*SP_STRIDE*2); // 2560 B
  float* sRedM = (float*)(smem + 16*SP_STRIDE*2 + 16*80*2);   // 256 B
  float* sRedS = sRedM + 64;                                  // 256 B
  float* sPol  = (float*)smem;  // aliased with sP: all reads complete before first sP write

  const int blk = blockIdx.x;
  const int b = blk / (NH*64);
  const int rem = blk % (NH*64);
  const int h = rem >> 6;
  const int qt = rem & 63;
  const int bh = b*NH + h;
  const size_t base = (size_t)bh << 16;

  const int t = threadIdx.x;
  const int w = t >> 6, l = t & 63, quad = l >> 4, lr = l & 15;

  { // load Q tile (16x64) and policy row
    int r = t >> 4, k0 = (t & 15)*4;
    *(uint2*)&sQ[r][k0] = *(const uint2*)(Q + base + (size_t)(qt*16 + r)*HD + k0);
    *(float4*)&sPol[t*4] = *(const float4*)(policy + b*NN + t*4);
  }
  __syncthreads();

  // ---- Phase 1: S^T = K Q^T (raw, unscaled) in registers
  f32x4 acc[16];
#pragma unroll
  for (int ct = 0; ct < 16; ct++) acc[ct] = (f32x4){0.f,0.f,0.f,0.f};
  f16x8 qf0 = as_f16x8(*(const uint4*)&sQ[lr][quad*8]);
  f16x8 qf1 = as_f16x8(*(const uint4*)&sQ[lr][32 + quad*8]);
#pragma unroll
  for (int ct = 0; ct < 16; ct++){
    int key0 = w*256 + ct*16;
    const f16* kp = K + base + (size_t)(key0 + lr)*HD + quad*8;
    f16x8 kf0 = as_f16x8(*(const uint4*)kp);
    f16x8 kf1 = as_f16x8(*(const uint4*)(kp + 32));
    acc[ct] = __builtin_amdgcn_mfma_f32_16x16x32_f16(kf0, qf0, acc[ct], 0, 0, 0);
    acc[ct] = __builtin_amdgcn_mfma_f32_16x16x32_f16(kf1, qf1, acc[ct], 0, 0, 0);
  }

  // ---- Phase 2: policy softmax in registers
  float m = -3.4e38f;
#pragma unroll
  for (int ct = 0; ct < 16; ct++)
#pragma unroll
    for (int i = 0; i < 4; i++) m = fmaxf(m, acc[ct][i]);
  m = fmaxf(m, __shfl_xor(m, 16));
  m = fmaxf(m, __shfl_xor(m, 32));
  if (l < 16) sRedM[w*16 + l] = m;
  __syncthreads();
  float m4 = fmaxf(fmaxf(sRedM[lr], sRedM[16 + lr]),
                   fmaxf(sRedM[32 + lr], sRedM[48 + lr]));

  const int qglob = qt*16 + lr;
  float sum = 0.f;
#pragma unroll
  for (int ct = 0; ct < 16; ct++){
    int keyb = w*256 + ct*16 + quad*4;
    float4 pol4 = *(const float4*)&sPol[keyb];
    const float* p4 = (const float*)&pol4;
#pragma unroll
    for (int i = 0; i < 4; i++){
      float pol = (keyb + i == qglob) ? 1.0f : p4[i];
      float e = __expf((acc[ct][i] - m4) * 0.125f) * pol;
      acc[ct][i] = e;
      sum += e;
    }
  }
  sum += __shfl_xor(sum, 16);
  sum += __shfl_xor(sum, 32);
  if (l < 16) sRedS[w*16 + l] = sum;
  __syncthreads();
  float tot = sRedS[lr] + sRedS[16 + lr] + sRedS[32 + lr] + sRedS[48 + lr];
  float inv = 1.0f / (tot + 1e-6f);
  const float addc = 1e-6f / 1024.0f;
#pragma unroll
  for (int ct = 0; ct < 16; ct++){
    f16x4 p;
#pragma unroll
    for (int i = 0; i < 4; i++) p[i] = (f16)((acc[ct][i] + addc) * inv);
    *(f16x4*)&sP[lr][w*256 + ct*16 + quad*4] = p;   // ds_write_b64
  }
  __syncthreads();

  // ---- Phase 3: O = P V^T (wave w covers its 256 keys), partial-reduce
  f32x4 o[4] = {};
#pragma unroll
  for (int s8 = 0; s8 < 8; s8++){
    int kb = w*256 + s8*32;
    f16x8 pf = as_f16x8(*(const uint4*)&sP[lr][kb + quad*8]);  // ds_read_b128
#pragma unroll
    for (int nt = 0; nt < 4; nt++){
      f16x8 vf = as_f16x8(*(const uint4*)(VT + base + (size_t)(nt*16 + lr)*NN + kb + quad*8));
      o[nt] = __builtin_amdgcn_mfma_f32_16x16x32_f16(pf, vf, o[nt], 0, 0, 0);
    }
  }
  __syncthreads();
  float* sPart = (float*)smem;   // reuse as [4][16][64] f32 partials
#pragma unroll
  for (int nt = 0; nt < 4; nt++)
#pragma unroll
    for (int i = 0; i < 4; i++)
      sPart[w*1024 + (quad*4 + i)*64 + nt*16 + lr] = o[nt][i];
  __syncthreads();
  {
    int o0 = t*4;
    int r = o0 >> 6, d = o0 & 63;
    f16x4 v;
#pragma unroll
    for (int j = 0; j < 4; j++){
      float s = sPart[o0 + j] + sPart[1024 + o0 + j] + sPart[2048 + o0 + j] + sPart[3072 + o0 + j];
      v[j] = (f16)s;
    }
    *(f16x4*)(O + (size_t)(b*NN + qt*16 + r)*NC + h*HD + d) = v;
  }
}

// ---------------- proj GEMM: [16384,768] x [768,768]^T + bias -> fp32 ----------------
__launch_bounds__(256)
__global__ void gemm_proj(const f16* __restrict__ A, const f16* __restrict__ W,
                          const float* __restrict__ bias, float* __restrict__ out){
  __shared__ f16 sA[64][40];
  __shared__ f16 sB[64][40];
  const int R0 = blockIdx.y*64, C0 = blockIdx.x*64;
  const int t = threadIdx.x;
  const int w = t >> 6, l = t & 63, quad = l >> 4, lr = l & 15;
  const int lrow = t >> 2, lk = (t & 3)*8;
  f32x4 acc[4] = {};
  for (int bk = 0; bk < NC; bk += 32){
    uint4 a = *(const uint4*)(A + (size_t)(R0 + lrow)*NC + bk + lk);
    uint4 b = *(const uint4*)(W + (size_t)(C0 + lrow)*NC + bk + lk);
    __syncthreads();
    *(uint4*)&sA[lrow][lk] = a;
    *(uint4*)&sB[lrow][lk] = b;
    __syncthreads();
    f16x8 af = as_f16x8(*(const uint4*)&sA[w*16 + lr][quad*8]);
#pragma unroll
    for (int nt = 0; nt < 4; nt++){
      f16x8 bf = as_f16x8(*(const uint4*)&sB[nt*16 + lr][quad*8]);
      acc[nt] = __builtin_amdgcn_mfma_f32_16x16x32_f16(af, bf, acc[nt], 0, 0, 0);
    }
  }
#pragma unroll
  for (int nt = 0; nt < 4; nt++){
    int colg = C0 + nt*16 + lr;
    float bv = bias[colg];
#pragma unroll
    for (int i = 0; i < 4; i++){
      int row = R0 + w*16 + quad*4 + i;
      out[(size_t)row*NC + colg] = acc[nt][i] + bv;
    }
  }
}

extern "C" void kernel_launch(void* const* d_in, const int* in_sizes, int n_in,
                              void* d_out, int out_size, void* d_ws, size_t ws_size,
                              hipStream_t stream) {
  const float* x      = (const float*)d_in[0];
  const float* policy = (const float*)d_in[1];
  const float* w_qkv  = (const float*)d_in[2];
  const float* w_proj = (const float*)d_in[3];
  const float* b_proj = (const float*)d_in[4];
  float* out = (float*)d_out;

  f16* x_h     = (f16*)d_ws;
  f16* wqkv_h  = x_h + (size_t)NM*NC;
  f16* wproj_h = wqkv_h + (size_t)QKVC*NC;
  f16* q_h     = wproj_h + (size_t)NC*NC;
  f16* k_h     = q_h + (size_t)NM*NC;
  f16* vt_h    = k_h + (size_t)NM*NC;
  f16* attn_h  = x_h;   // x dead after gemm_qkv -> reuse

  cvt_f32_f16<<<(NM*NC/4 + 255)/256, 256, 0, stream>>>(x, x_h, NM*NC/4);
  cvt_f32_f16<<<(QKVC*NC/4 + 255)/256, 256, 0, stream>>>(w_qkv, wqkv_h, QKVC*NC/4);
  cvt_f32_f16<<<(NC*NC/4 + 255)/256, 256, 0, stream>>>(w_proj, wproj_h, NC*NC/4);

  gemm_qkv<<<dim3(QKVC/64, NM/64), 256, 0, stream>>>(x_h, wqkv_h, q_h, k_h, vt_h);

  attn_kernel<<<dim3(NB*NH*(NN/16)), 256, 0, stream>>>(q_h, k_h, vt_h, policy, attn_h);

  gemm_proj<<<dim3(NC/64, NM/64), 256, 0, stream>>>(attn_h, wproj_h, b_proj, out);
}

// Round 3
// 522.769 us; speedup vs baseline: 1.5684x; 1.3551x over previous
//
#include <hip/hip_runtime.h>

// Attention with policy-softmax, MI355X (gfx950).
// Shapes: B=16, N=1024, C=768, H=12, hd=64.
// R3: flash-style attention — 128 queries/block (32/wave), key-chunks of 128,
// online softmax in registers, Q/K/V read direct from global (MFMA-layout
// contiguous), per-wave private LDS P-slice, ZERO barriers in main loop.
// Exact +eps/N term via separate Vsum (column sums of V) kernel.

#define NB 16
#define NN 1024
#define NC 768
#define NH 12
#define HD 64
#define NM (NB*NN)      // 16384
#define QKVC (3*NC)     // 2304

typedef _Float16 f16;
typedef _Float16 f16x8 __attribute__((ext_vector_type(8)));
typedef _Float16 f16x4 __attribute__((ext_vector_type(4)));
typedef float f32x4 __attribute__((ext_vector_type(4)));

__device__ inline f16x8 as_f16x8(uint4 u){
  union { uint4 u; f16x8 h; } v; v.u = u; return v.h;
}

// ---------------- fp32 -> f16 convert ----------------
__global__ void cvt_f32_f16(const float* __restrict__ in, f16* __restrict__ out, int n4){
  int i = blockIdx.x*blockDim.x + threadIdx.x;
  if (i < n4){
    float4 v = ((const float4*)in)[i];
    f16x4 h; h[0]=(f16)v.x; h[1]=(f16)v.y; h[2]=(f16)v.z; h[3]=(f16)v.w;
    ((f16x4*)out)[i] = h;
  }
}

// ---------------- QKV GEMM: [16384,768] x [2304,768]^T -----------------
__launch_bounds__(256)
__global__ void gemm_qkv(const f16* __restrict__ X, const f16* __restrict__ W,
                         f16* __restrict__ Q, f16* __restrict__ K, f16* __restrict__ VT){
  __shared__ f16 sA[64][40];
  __shared__ f16 sB[64][40];
  const int R0 = blockIdx.y*64, C0 = blockIdx.x*64;
  const int t = threadIdx.x;
  const int w = t >> 6, l = t & 63, quad = l >> 4, lr = l & 15;
  const int lrow = t >> 2, lk = (t & 3)*8;
  f32x4 acc[4] = {};
  for (int bk = 0; bk < NC; bk += 32){
    uint4 a = *(const uint4*)(X + (size_t)(R0 + lrow)*NC + bk + lk);
    uint4 b = *(const uint4*)(W + (size_t)(C0 + lrow)*NC + bk + lk);
    __syncthreads();
    *(uint4*)&sA[lrow][lk] = a;
    *(uint4*)&sB[lrow][lk] = b;
    __syncthreads();
    f16x8 af = as_f16x8(*(const uint4*)&sA[w*16 + lr][quad*8]);
#pragma unroll
    for (int nt = 0; nt < 4; nt++){
      f16x8 bf = as_f16x8(*(const uint4*)&sB[nt*16 + lr][quad*8]);
      acc[nt] = __builtin_amdgcn_mfma_f32_16x16x32_f16(af, bf, acc[nt], 0, 0, 0);
    }
  }
#pragma unroll
  for (int nt = 0; nt < 4; nt++){
    int colg = C0 + nt*16 + lr;
    int type = colg / NC;
    int rem  = colg - type*NC;
    int hh = rem >> 6, d = rem & 63;
#pragma unroll
    for (int i = 0; i < 4; i++){
      int row = R0 + w*16 + quad*4 + i;
      int bb = row >> 10, np = row & 1023;
      int bh = bb*NH + hh;
      f16 v = (f16)acc[nt][i];
      if (type == 0)      Q[(bh << 16) + (np << 6) + d] = v;
      else if (type == 1) K[(bh << 16) + (np << 6) + d] = v;
      else                VT[(bh << 16) + (d << 10) + np] = v;
    }
  }
}

// ---------------- Vsum: column sums of V per (b,h) ----------------
// VT is [bh][d][n]; vsum[bh][d] = sum_n VT[bh][d][n]. One block per bh.
__global__ void vsum_kernel(const f16* __restrict__ VT, float* __restrict__ vsum){
  int bh = blockIdx.x;
  int t = threadIdx.x;
  int row = t >> 2, part = t & 3;
  const uint4* p = (const uint4*)(VT + ((size_t)bh << 16) + row*NN + part*256);
  float s = 0.f;
#pragma unroll
  for (int i = 0; i < 32; i++){
    f16x8 v = as_f16x8(p[i]);
#pragma unroll
    for (int j = 0; j < 8; j++) s += (float)v[j];
  }
  __shared__ float sR[64][4];
  sR[row][part] = s;
  __syncthreads();
  if (t < 64) vsum[bh*64 + t] = sR[t][0] + sR[t][1] + sR[t][2] + sR[t][3];
}

// ---------------- fused flash-style policy-softmax attention ----------------
// Grid: B*H*(N/128) = 1536 blocks, 256 threads = 4 independent waves.
// Wave w owns queries [qt*128 + w*32, +32) as two 16-query MFMA tiles.
// Loop over 8 chunks of 128 keys:
//   S^T = K Q^T (MFMA, K direct global), online softmax in regs,
//   P -> private LDS slice (f16), O += P V^T (V direct global), O-rescale.
// No __syncthreads in the loop (per-wave LDS slices only).
#define PSTR 136   // f16 row stride: 272B, 16B-aligned; b64/b128 conflict-free
__launch_bounds__(256, 3)
__global__ void attn_kernel(const f16* __restrict__ Q, const f16* __restrict__ K,
                            const f16* __restrict__ VT, const float* __restrict__ policy,
                            const float* __restrict__ vsum, f16* __restrict__ O){
  __shared__ f16 sP[4][2][16][PSTR];   // 34816 B

  const int blk = blockIdx.x;
  const int b = blk / (NH*8);
  const int rem = blk % (NH*8);
  const int h = rem >> 3;
  const int qt = rem & 7;
  const int bh = b*NH + h;
  const size_t base = (size_t)bh << 16;

  const int t = threadIdx.x;
  const int w = t >> 6, l = t & 63, quad = l >> 4, lr = l & 15;
  const int q0 = qt*128 + w*32;
  const int qrow = q0 + lr;            // qtile0 query for this lane; qtile1 = +16

  // Q fragments: B-operand layout, contiguous 16B global reads
  f16x8 qf[2][2];
#pragma unroll
  for (int tq = 0; tq < 2; tq++)
#pragma unroll
    for (int hf = 0; hf < 2; hf++)
      qf[tq][hf] = as_f16x8(*(const uint4*)(Q + base + (size_t)(q0 + tq*16 + lr)*HD + hf*32 + quad*8));

  float vs[4];
#pragma unroll
  for (int nt = 0; nt < 4; nt++) vs[nt] = vsum[bh*64 + nt*16 + lr];

  float m_run[2] = {-INFINITY, -INFINITY};
  float l_run[2] = {0.f, 0.f};
  f32x4 o[2][4] = {};

  for (int c = 0; c < 8; c++){
    const int key0 = c*128;
    // ---- S^T chunk: lane holds keys {key0+ct*16+quad*4+i} for query lr (per qtile)
    f32x4 accA[8], accB[8];
#pragma unroll
    for (int ct = 0; ct < 8; ct++){ accA[ct] = (f32x4){0,0,0,0}; accB[ct] = (f32x4){0,0,0,0}; }
#pragma unroll
    for (int ct = 0; ct < 8; ct++){
      const f16* kp = K + base + (size_t)(key0 + ct*16 + lr)*HD + quad*8;
      f16x8 k0 = as_f16x8(*(const uint4*)kp);
      f16x8 k1 = as_f16x8(*(const uint4*)(kp + 32));
      accA[ct] = __builtin_amdgcn_mfma_f32_16x16x32_f16(k0, qf[0][0], accA[ct], 0, 0, 0);
      accA[ct] = __builtin_amdgcn_mfma_f32_16x16x32_f16(k1, qf[0][1], accA[ct], 0, 0, 0);
      accB[ct] = __builtin_amdgcn_mfma_f32_16x16x32_f16(k0, qf[1][0], accB[ct], 0, 0, 0);
      accB[ct] = __builtin_amdgcn_mfma_f32_16x16x32_f16(k1, qf[1][1], accB[ct], 0, 0, 0);
    }
    // ---- chunk max (per query = lr)
    float mcA = -INFINITY, mcB = -INFINITY;
#pragma unroll
    for (int ct = 0; ct < 8; ct++)
#pragma unroll
      for (int i = 0; i < 4; i++){ mcA = fmaxf(mcA, accA[ct][i]); mcB = fmaxf(mcB, accB[ct][i]); }
    mcA = fmaxf(mcA, __shfl_xor(mcA, 16)); mcA = fmaxf(mcA, __shfl_xor(mcA, 32));
    mcB = fmaxf(mcB, __shfl_xor(mcB, 16)); mcB = fmaxf(mcB, __shfl_xor(mcB, 32));
    float mnA = fmaxf(m_run[0], mcA), mnB = fmaxf(m_run[1], mcB);
    float alA = __expf((m_run[0] - mnA)*0.125f);
    float alB = __expf((m_run[1] - mnB)*0.125f);
    m_run[0] = mnA; m_run[1] = mnB;

    // ---- exp * policy, write P (f16) to private LDS slice
    float sA = 0.f, sB = 0.f;
#pragma unroll
    for (int ct = 0; ct < 8; ct++){
      int kb = key0 + ct*16 + quad*4;
      float4 pol4 = *(const float4*)(policy + b*NN + kb);
      const float* p4 = (const float*)&pol4;
      f16x4 pA, pB;
#pragma unroll
      for (int i = 0; i < 4; i++){
        float polA = (kb + i == qrow)      ? 1.0f : p4[i];
        float polB = (kb + i == qrow + 16) ? 1.0f : p4[i];
        float eA = __expf((accA[ct][i] - mnA)*0.125f) * polA;
        float eB = __expf((accB[ct][i] - mnB)*0.125f) * polB;
        sA += eA; sB += eB;
        pA[i] = (f16)eA; pB[i] = (f16)eB;
      }
      *(f16x4*)&sP[w][0][lr][ct*16 + quad*4] = pA;
      *(f16x4*)&sP[w][1][lr][ct*16 + quad*4] = pB;
    }
    sA += __shfl_xor(sA, 16); sA += __shfl_xor(sA, 32);
    sB += __shfl_xor(sB, 16); sB += __shfl_xor(sB, 32);
    l_run[0] = l_run[0]*alA + sA;
    l_run[1] = l_run[1]*alB + sB;

    // ---- rescale O (alpha is per-query=lr; O rows are queries quad*4+i)
    float aqA[4], aqB[4];
#pragma unroll
    for (int i = 0; i < 4; i++){ aqA[i] = __shfl(alA, quad*4 + i); aqB[i] = __shfl(alB, quad*4 + i); }
#pragma unroll
    for (int nt = 0; nt < 4; nt++)
#pragma unroll
      for (int i = 0; i < 4; i++){ o[0][nt][i] *= aqA[i]; o[1][nt][i] *= aqB[i]; }

    // ---- O += P V^T  (V direct global, contiguous 16B)
#pragma unroll
    for (int s8 = 0; s8 < 4; s8++){
      f16x8 pfA = as_f16x8(*(const uint4*)&sP[w][0][lr][s8*32 + quad*8]);
      f16x8 pfB = as_f16x8(*(const uint4*)&sP[w][1][lr][s8*32 + quad*8]);
#pragma unroll
      for (int nt = 0; nt < 4; nt++){
        f16x8 vf = as_f16x8(*(const uint4*)(VT + base + (size_t)(nt*16 + lr)*NN + key0 + s8*32 + quad*8));
        o[0][nt] = __builtin_amdgcn_mfma_f32_16x16x32_f16(pfA, vf, o[0][nt], 0, 0, 0);
        o[1][nt] = __builtin_amdgcn_mfma_f32_16x16x32_f16(pfB, vf, o[1][nt], 0, 0, 0);
      }
    }
  }

  // ---- epilogue: out = (O + (eps/N)*Vsum) / (l + eps)
  const float addc = 1e-6f / 1024.0f;
#pragma unroll
  for (int tq = 0; tq < 2; tq++){
    float invq[4];
#pragma unroll
    for (int i = 0; i < 4; i++){
      float li = __shfl(l_run[tq], quad*4 + i);
      invq[i] = 1.0f / (li + 1e-6f);
    }
#pragma unroll
    for (int i = 0; i < 4; i++){
      int row = q0 + tq*16 + quad*4 + i;
      f16* op = O + (size_t)(b*NN + row)*NC + h*HD;
#pragma unroll
      for (int nt = 0; nt < 4; nt++)
        op[nt*16 + lr] = (f16)((o[tq][nt][i] + addc*vs[nt]) * invq[i]);
    }
  }
}

// ---------------- proj GEMM: [16384,768] x [768,768]^T + bias -> fp32 ----------------
__launch_bounds__(256)
__global__ void gemm_proj(const f16* __restrict__ A, const f16* __restrict__ W,
                          const float* __restrict__ bias, float* __restrict__ out){
  __shared__ f16 sA[64][40];
  __shared__ f16 sB[64][40];
  const int R0 = blockIdx.y*64, C0 = blockIdx.x*64;
  const int t = threadIdx.x;
  const int w = t >> 6, l = t & 63, quad = l >> 4, lr = l & 15;
  const int lrow = t >> 2, lk = (t & 3)*8;
  f32x4 acc[4] = {};
  for (int bk = 0; bk < NC; bk += 32){
    uint4 a = *(const uint4*)(A + (size_t)(R0 + lrow)*NC + bk + lk);
    uint4 b = *(const uint4*)(W + (size_t)(C0 + lrow)*NC + bk + lk);
    __syncthreads();
    *(uint4*)&sA[lrow][lk] = a;
    *(uint4*)&sB[lrow][lk] = b;
    __syncthreads();
    f16x8 af = as_f16x8(*(const uint4*)&sA[w*16 + lr][quad*8]);
#pragma unroll
    for (int nt = 0; nt < 4; nt++){
      f16x8 bf = as_f16x8(*(const uint4*)&sB[nt*16 + lr][quad*8]);
      acc[nt] = __builtin_amdgcn_mfma_f32_16x16x32_f16(af, bf, acc[nt], 0, 0, 0);
    }
  }
#pragma unroll
  for (int nt = 0; nt < 4; nt++){
    int colg = C0 + nt*16 + lr;
    float bv = bias[colg];
#pragma unroll
    for (int i = 0; i < 4; i++){
      int row = R0 + w*16 + quad*4 + i;
      out[(size_t)row*NC + colg] = acc[nt][i] + bv;
    }
  }
}

extern "C" void kernel_launch(void* const* d_in, const int* in_sizes, int n_in,
                              void* d_out, int out_size, void* d_ws, size_t ws_size,
                              hipStream_t stream) {
  const float* x      = (const float*)d_in[0];
  const float* policy = (const float*)d_in[1];
  const float* w_qkv  = (const float*)d_in[2];
  const float* w_proj = (const float*)d_in[3];
  const float* b_proj = (const float*)d_in[4];
  float* out = (float*)d_out;

  f16* x_h     = (f16*)d_ws;
  f16* wqkv_h  = x_h + (size_t)NM*NC;
  f16* wproj_h = wqkv_h + (size_t)QKVC*NC;
  f16* q_h     = wproj_h + (size_t)NC*NC;
  f16* k_h     = q_h + (size_t)NM*NC;
  f16* vt_h    = k_h + (size_t)NM*NC;
  float* vsum_f = (float*)(vt_h + (size_t)NM*NC);  // 192*64 floats
  f16* attn_h  = x_h;   // x dead after gemm_qkv -> reuse

  cvt_f32_f16<<<(NM*NC/4 + 255)/256, 256, 0, stream>>>(x, x_h, NM*NC/4);
  cvt_f32_f16<<<(QKVC*NC/4 + 255)/256, 256, 0, stream>>>(w_qkv, wqkv_h, QKVC*NC/4);
  cvt_f32_f16<<<(NC*NC/4 + 255)/256, 256, 0, stream>>>(w_proj, wproj_h, NC*NC/4);

  gemm_qkv<<<dim3(QKVC/64, NM/64), 256, 0, stream>>>(x_h, wqkv_h, q_h, k_h, vt_h);

  vsum_kernel<<<dim3(NB*NH), 256, 0, stream>>>(vt_h, vsum_f);

  attn_kernel<<<dim3(NB*NH*(NN/128)), 256, 0, stream>>>(q_h, k_h, vt_h, policy, vsum_f, attn_h);

  gemm_proj<<<dim3(NC/64, NM/64), 256, 0, stream>>>(attn_h, wproj_h, b_proj, out);
}

// Round 5
// 491.442 us; speedup vs baseline: 1.6684x; 1.0637x over previous
//
#include <hip/hip_runtime.h>

// Attention with policy-softmax, MI355X (gfx950).
// Shapes: B=16, N=1024, C=768, H=12, hd=64.
// R4b: compile fix (cvt_pkrtz returns __fp16x2, not _Float16x2).
// (a) attention: no-max-subtract softmax (exact via E=exp(max) eps-fix in
// epilogue), scale folded into Q (exp2 path), l via ones-MFMA, pkrtz packing,
// zero cross-lane ops in main loop. (b) GEMMs: 128x128 tile, 4x4 acc/wave,
// global_load_lds width=16 (m97 pattern).

#define NB 16
#define NN 1024
#define NC 768
#define NH 12
#define HD 64
#define NM (NB*NN)      // 16384
#define QKVC (3*NC)     // 2304
#define QSCALE 0.18033688011112042f   // 0.125 * log2(e)

typedef _Float16 f16;
typedef _Float16 f16x8 __attribute__((ext_vector_type(8)));
typedef _Float16 f16x4 __attribute__((ext_vector_type(4)));
typedef __fp16 fp16x2 __attribute__((ext_vector_type(2)));   // cvt_pkrtz native type
typedef float f32x4 __attribute__((ext_vector_type(4)));

__device__ inline f16x8 as_f16x8(uint4 u){
  union { uint4 u; f16x8 h; } v; v.u = u; return v.h;
}

// async global->LDS, 16B per lane; lds ptr must be wave-uniform (lane l lands at +l*16B)
__device__ inline void gl_lds16(const f16* g, f16* l){
  __builtin_amdgcn_global_load_lds(
      (const __attribute__((address_space(1))) void*)g,
      (__attribute__((address_space(3))) void*)l, 16, 0, 0);
}

// ---------------- fp32 -> f16 convert ----------------
__global__ void cvt_f32_f16(const float* __restrict__ in, f16* __restrict__ out, int n4){
  int i = blockIdx.x*blockDim.x + threadIdx.x;
  if (i < n4){
    float4 v = ((const float4*)in)[i];
    f16x4 h; h[0]=(f16)v.x; h[1]=(f16)v.y; h[2]=(f16)v.z; h[3]=(f16)v.w;
    ((f16x4*)out)[i] = h;
  }
}

// ---------------- QKV GEMM: [16384,768] x [2304,768]^T, 128x128 tile ----------------
__launch_bounds__(256)
__global__ void gemm_qkv(const f16* __restrict__ X, const f16* __restrict__ W,
                         f16* __restrict__ Q, f16* __restrict__ K, f16* __restrict__ VT){
  __shared__ f16 sA[128*32];   // 8 KB, row-major [row][k], stride 32
  __shared__ f16 sB[128*32];
  const int R0 = blockIdx.y*128, C0 = blockIdx.x*128;
  const int t = threadIdx.x;
  const int w = t >> 6, l = t & 63, quad = l >> 4, lr = l & 15;
  const int wr = w >> 1, wc = w & 1;
  const int row0 = t >> 2, kc0 = (t & 3)*8;
  f32x4 acc[4][4] = {};
  for (int bk = 0; bk < NC; bk += 32){
#pragma unroll
    for (int r = 0; r < 2; r++){
      int row = r*64 + row0;
      gl_lds16(X + (size_t)(R0 + row)*NC + bk + kc0, sA + r*2048 + w*512);
      gl_lds16(W + (size_t)(C0 + row)*NC + bk + kc0, sB + r*2048 + w*512);
    }
    __syncthreads();
    f16x8 af[4], bf[4];
#pragma unroll
    for (int mt = 0; mt < 4; mt++)
      af[mt] = as_f16x8(*(const uint4*)(sA + (wr*64 + mt*16 + lr)*32 + quad*8));
#pragma unroll
    for (int nt = 0; nt < 4; nt++)
      bf[nt] = as_f16x8(*(const uint4*)(sB + (wc*64 + nt*16 + lr)*32 + quad*8));
#pragma unroll
    for (int mt = 0; mt < 4; mt++)
#pragma unroll
      for (int nt = 0; nt < 4; nt++)
        acc[mt][nt] = __builtin_amdgcn_mfma_f32_16x16x32_f16(af[mt], bf[nt], acc[mt][nt], 0, 0, 0);
    __syncthreads();
  }
  // scatter into Q / K / V^T. type uniform per block (128 | 768).
  const int type = C0 / NC;
#pragma unroll
  for (int nt = 0; nt < 4; nt++){
    int colg = C0 + wc*64 + nt*16 + lr;
    int rem  = colg - type*NC;
    int hh = rem >> 6, d = rem & 63;
#pragma unroll
    for (int mt = 0; mt < 4; mt++)
#pragma unroll
      for (int i = 0; i < 4; i++){
        int row = R0 + wr*64 + mt*16 + quad*4 + i;
        int bb = row >> 10, np = row & 1023;
        int bh = bb*NH + hh;
        float a = acc[mt][nt][i];
        if (type == 0)      Q[(bh << 16) + (np << 6) + d] = (f16)(a * QSCALE);
        else if (type == 1) K[(bh << 16) + (np << 6) + d] = (f16)a;
        else                VT[(bh << 16) + (d << 10) + np] = (f16)a;
      }
  }
}

// ---------------- Vsum: column sums of V per (b,h) ----------------
__global__ void vsum_kernel(const f16* __restrict__ VT, float* __restrict__ vsum){
  int bh = blockIdx.x;
  int t = threadIdx.x;
  int row = t >> 2, part = t & 3;
  const uint4* p = (const uint4*)(VT + ((size_t)bh << 16) + row*NN + part*256);
  float s = 0.f;
#pragma unroll
  for (int i = 0; i < 32; i++){
    f16x8 v = as_f16x8(p[i]);
#pragma unroll
    for (int j = 0; j < 8; j++) s += (float)v[j];
  }
  __shared__ float sR[64][4];
  sR[row][part] = s;
  __syncthreads();
  if (t < 64) vsum[bh*64 + t] = sR[t][0] + sR[t][1] + sR[t][2] + sR[t][3];
}

// ---------------- fused policy-softmax attention (no-max-subtract) ----------------
// Grid: B*H*(N/128) = 1536 blocks, 256 thr = 4 independent waves (32 queries each).
// Q pre-scaled by 0.125*log2e -> e = exp2(acc) directly. No cross-lane ops in loop.
// l accumulated by MFMA with ones-B. Epilogue: out = (O + eps/N*E*Vsum)/(l + eps*E),
// E = exp2(rowmax) — exact reference semantics.
#define PSTR 136   // f16 row stride: 272B, 16B-aligned
__launch_bounds__(256, 3)
__global__ void attn_kernel(const f16* __restrict__ Q, const f16* __restrict__ K,
                            const f16* __restrict__ VT, const float* __restrict__ policy,
                            const float* __restrict__ vsum, f16* __restrict__ O){
  __shared__ f16 sP[4][2][16][PSTR];   // 34816 B
  __shared__ float sPol[1024];         // 4096 B

  const int blk = blockIdx.x;
  const int b = blk / (NH*8);
  const int rem = blk % (NH*8);
  const int h = rem >> 3;
  const int qt = rem & 7;
  const int bh = b*NH + h;
  const size_t base = (size_t)bh << 16;

  const int t = threadIdx.x;
  const int w = t >> 6, l = t & 63, quad = l >> 4, lr = l & 15;
  const int q0 = qt*128 + w*32;
  const int qrow = q0 + lr;

  *(float4*)&sPol[t*4] = *(const float4*)(policy + b*NN + t*4);

  // Q fragments (pre-scaled), contiguous 16B global reads
  f16x8 qf[2][2];
#pragma unroll
  for (int tq = 0; tq < 2; tq++)
#pragma unroll
    for (int hf = 0; hf < 2; hf++)
      qf[tq][hf] = as_f16x8(*(const uint4*)(Q + base + (size_t)(q0 + tq*16 + lr)*HD + hf*32 + quad*8));

  float vs[4];
#pragma unroll
  for (int nt = 0; nt < 4; nt++) vs[nt] = vsum[bh*64 + nt*16 + lr];

  f16x8 ones;
#pragma unroll
  for (int j = 0; j < 8; j++) ones[j] = (f16)1.0f;

  float m_run[2] = {-INFINITY, -INFINITY};
  f32x4 acc_l[2] = {};
  f32x4 o[2][4] = {};

  __syncthreads();   // sPol ready

  for (int c = 0; c < 8; c++){
    const int key0 = c*128;
    // ---- S^T chunk (scaled scores in log2 domain)
    f32x4 accA[8], accB[8];
#pragma unroll
    for (int ct = 0; ct < 8; ct++){ accA[ct] = (f32x4){0,0,0,0}; accB[ct] = (f32x4){0,0,0,0}; }
#pragma unroll
    for (int ct = 0; ct < 8; ct++){
      const f16* kp = K + base + (size_t)(key0 + ct*16 + lr)*HD + quad*8;
      f16x8 k0 = as_f16x8(*(const uint4*)kp);
      f16x8 k1 = as_f16x8(*(const uint4*)(kp + 32));
      accA[ct] = __builtin_amdgcn_mfma_f32_16x16x32_f16(k0, qf[0][0], accA[ct], 0, 0, 0);
      accA[ct] = __builtin_amdgcn_mfma_f32_16x16x32_f16(k1, qf[0][1], accA[ct], 0, 0, 0);
      accB[ct] = __builtin_amdgcn_mfma_f32_16x16x32_f16(k0, qf[1][0], accB[ct], 0, 0, 0);
      accB[ct] = __builtin_amdgcn_mfma_f32_16x16x32_f16(k1, qf[1][1], accB[ct], 0, 0, 0);
    }
    // ---- P = exp2(acc) * pol (f16), local max tracking only
    float mA = m_run[0], mB = m_run[1];
    if (c != qt){
#pragma unroll
      for (int ct = 0; ct < 8; ct++){
        int kb = ct*16 + quad*4;
        float4 pol4 = *(const float4*)&sPol[key0 + kb];
        const float* p4 = (const float*)&pol4;
        mA = fmaxf(mA, fmaxf(fmaxf(accA[ct][0], accA[ct][1]), fmaxf(accA[ct][2], accA[ct][3])));
        mB = fmaxf(mB, fmaxf(fmaxf(accB[ct][0], accB[ct][1]), fmaxf(accB[ct][2], accB[ct][3])));
        union { f16x4 v; fp16x2 h[2]; } uA, uB;
        uA.h[0] = __builtin_amdgcn_cvt_pkrtz(exp2f(accA[ct][0])*p4[0], exp2f(accA[ct][1])*p4[1]);
        uA.h[1] = __builtin_amdgcn_cvt_pkrtz(exp2f(accA[ct][2])*p4[2], exp2f(accA[ct][3])*p4[3]);
        uB.h[0] = __builtin_amdgcn_cvt_pkrtz(exp2f(accB[ct][0])*p4[0], exp2f(accB[ct][1])*p4[1]);
        uB.h[1] = __builtin_amdgcn_cvt_pkrtz(exp2f(accB[ct][2])*p4[2], exp2f(accB[ct][3])*p4[3]);
        *(f16x4*)&sP[w][0][lr][kb] = uA.v;
        *(f16x4*)&sP[w][1][lr][kb] = uB.v;
      }
    } else {
#pragma unroll
      for (int ct = 0; ct < 8; ct++){
        int kb = ct*16 + quad*4;
        float4 pol4 = *(const float4*)&sPol[key0 + kb];
        const float* p4 = (const float*)&pol4;
        float eA[4], eB[4];
#pragma unroll
        for (int i = 0; i < 4; i++){
          int kg = key0 + kb + i;
          float polA = (kg == qrow)      ? 1.0f : p4[i];
          float polB = (kg == qrow + 16) ? 1.0f : p4[i];
          mA = fmaxf(mA, accA[ct][i]); mB = fmaxf(mB, accB[ct][i]);
          eA[i] = exp2f(accA[ct][i]) * polA;
          eB[i] = exp2f(accB[ct][i]) * polB;
        }
        union { f16x4 v; fp16x2 h[2]; } uA, uB;
        uA.h[0] = __builtin_amdgcn_cvt_pkrtz(eA[0], eA[1]);
        uA.h[1] = __builtin_amdgcn_cvt_pkrtz(eA[2], eA[3]);
        uB.h[0] = __builtin_amdgcn_cvt_pkrtz(eB[0], eB[1]);
        uB.h[1] = __builtin_amdgcn_cvt_pkrtz(eB[2], eB[3]);
        *(f16x4*)&sP[w][0][lr][kb] = uA.v;
        *(f16x4*)&sP[w][1][lr][kb] = uB.v;
      }
    }
    m_run[0] = mA; m_run[1] = mB;

    // ---- O += P V^T ; l += P * ones (both MFMA)
#pragma unroll
    for (int s8 = 0; s8 < 4; s8++){
      f16x8 pfA = as_f16x8(*(const uint4*)&sP[w][0][lr][s8*32 + quad*8]);
      f16x8 pfB = as_f16x8(*(const uint4*)&sP[w][1][lr][s8*32 + quad*8]);
      acc_l[0] = __builtin_amdgcn_mfma_f32_16x16x32_f16(pfA, ones, acc_l[0], 0, 0, 0);
      acc_l[1] = __builtin_amdgcn_mfma_f32_16x16x32_f16(pfB, ones, acc_l[1], 0, 0, 0);
#pragma unroll
      for (int nt = 0; nt < 4; nt++){
        f16x8 vf = as_f16x8(*(const uint4*)(VT + base + (size_t)(nt*16 + lr)*NN + key0 + s8*32 + quad*8));
        o[0][nt] = __builtin_amdgcn_mfma_f32_16x16x32_f16(pfA, vf, o[0][nt], 0, 0, 0);
        o[1][nt] = __builtin_amdgcn_mfma_f32_16x16x32_f16(pfB, vf, o[1][nt], 0, 0, 0);
      }
    }
  }

  // ---- epilogue: out = (O + eps/N * E * Vsum) / (l + eps * E)
#pragma unroll
  for (int tq = 0; tq < 2; tq++){
    float mq = m_run[tq];
    mq = fmaxf(mq, __shfl_xor(mq, 16));
    mq = fmaxf(mq, __shfl_xor(mq, 32));   // per-query (lr) global max, all lanes
#pragma unroll
    for (int i = 0; i < 4; i++){
      float mi = __shfl(mq, quad*4 + i);  // max for query row quad*4+i
      float E  = exp2f(mi);
      float li = acc_l[tq][i];            // row-sum for this query
      float inv = 1.0f / (li + 1e-6f*E);
      float ec  = (1e-6f/1024.0f)*E;
      int row = q0 + tq*16 + quad*4 + i;
      f16* op = O + (size_t)(b*NN + row)*NC + h*HD;
#pragma unroll
      for (int nt = 0; nt < 4; nt++)
        op[nt*16 + lr] = (f16)((o[tq][nt][i] + ec*vs[nt]) * inv);
    }
  }
}

// ---------------- proj GEMM: [16384,768] x [768,768]^T + bias -> fp32, 128x128 ----------------
__launch_bounds__(256)
__global__ void gemm_proj(const f16* __restrict__ A, const f16* __restrict__ W,
                          const float* __restrict__ bias, float* __restrict__ out){
  __shared__ f16 sA[128*32];
  __shared__ f16 sB[128*32];
  const int R0 = blockIdx.y*128, C0 = blockIdx.x*128;
  const int t = threadIdx.x;
  const int w = t >> 6, l = t & 63, quad = l >> 4, lr = l & 15;
  const int wr = w >> 1, wc = w & 1;
  const int row0 = t >> 2, kc0 = (t & 3)*8;
  f32x4 acc[4][4] = {};
  for (int bk = 0; bk < NC; bk += 32){
#pragma unroll
    for (int r = 0; r < 2; r++){
      int row = r*64 + row0;
      gl_lds16(A + (size_t)(R0 + row)*NC + bk + kc0, sA + r*2048 + w*512);
      gl_lds16(W + (size_t)(C0 + row)*NC + bk + kc0, sB + r*2048 + w*512);
    }
    __syncthreads();
    f16x8 af[4], bf[4];
#pragma unroll
    for (int mt = 0; mt < 4; mt++)
      af[mt] = as_f16x8(*(const uint4*)(sA + (wr*64 + mt*16 + lr)*32 + quad*8));
#pragma unroll
    for (int nt = 0; nt < 4; nt++)
      bf[nt] = as_f16x8(*(const uint4*)(sB + (wc*64 + nt*16 + lr)*32 + quad*8));
#pragma unroll
    for (int mt = 0; mt < 4; mt++)
#pragma unroll
      for (int nt = 0; nt < 4; nt++)
        acc[mt][nt] = __builtin_amdgcn_mfma_f32_16x16x32_f16(af[mt], bf[nt], acc[mt][nt], 0, 0, 0);
    __syncthreads();
  }
#pragma unroll
  for (int nt = 0; nt < 4; nt++){
    int colg = C0 + wc*64 + nt*16 + lr;
    float bv = bias[colg];
#pragma unroll
    for (int mt = 0; mt < 4; mt++)
#pragma unroll
      for (int i = 0; i < 4; i++){
        int row = R0 + wr*64 + mt*16 + quad*4 + i;
        out[(size_t)row*NC + colg] = acc[mt][nt][i] + bv;
      }
  }
}

extern "C" void kernel_launch(void* const* d_in, const int* in_sizes, int n_in,
                              void* d_out, int out_size, void* d_ws, size_t ws_size,
                              hipStream_t stream) {
  const float* x      = (const float*)d_in[0];
  const float* policy = (const float*)d_in[1];
  const float* w_qkv  = (const float*)d_in[2];
  const float* w_proj = (const float*)d_in[3];
  const float* b_proj = (const float*)d_in[4];
  float* out = (float*)d_out;

  f16* x_h     = (f16*)d_ws;
  f16* wqkv_h  = x_h + (size_t)NM*NC;
  f16* wproj_h = wqkv_h + (size_t)QKVC*NC;
  f16* q_h     = wproj_h + (size_t)NC*NC;
  f16* k_h     = q_h + (size_t)NM*NC;
  f16* vt_h    = k_h + (size_t)NM*NC;
  float* vsum_f = (float*)(vt_h + (size_t)NM*NC);
  f16* attn_h  = x_h;   // x dead after gemm_qkv -> reuse

  cvt_f32_f16<<<(NM*NC/4 + 255)/256, 256, 0, stream>>>(x, x_h, NM*NC/4);
  cvt_f32_f16<<<(QKVC*NC/4 + 255)/256, 256, 0, stream>>>(w_qkv, wqkv_h, QKVC*NC/4);
  cvt_f32_f16<<<(NC*NC/4 + 255)/256, 256, 0, stream>>>(w_proj, wproj_h, NC*NC/4);

  gemm_qkv<<<dim3(QKVC/128, NM/128), 256, 0, stream>>>(x_h, wqkv_h, q_h, k_h, vt_h);

  vsum_kernel<<<dim3(NB*NH), 256, 0, stream>>>(vt_h, vsum_f);

  attn_kernel<<<dim3(NB*NH*(NN/128)), 256, 0, stream>>>(q_h, k_h, vt_h, policy, vsum_f, attn_h);

  gemm_proj<<<dim3(NC/128, NM/128), 256, 0, stream>>>(attn_h, wproj_h, b_proj, out);
}

// Round 6
// 466.680 us; speedup vs baseline: 1.7569x; 1.0531x over previous
//
#include <hip/hip_runtime.h>

// Attention with policy-softmax, MI355X (gfx950).
// Shapes: B=16, N=1024, C=768, H=12, hd=64.
// R6: attn spill fix — S-phase split into two 64-key halves (32 transient
// acc VGPRs instead of 64, peak live ~130 < 170 budget at 3 waves/EU);
// XCD-aware grid swizzle (same-bh q-blocks stride-192 => same XCD L2).
// GEMMs unchanged (128x128 tile, global_load_lds width=16).

#define NB 16
#define NN 1024
#define NC 768
#define NH 12
#define HD 64
#define NM (NB*NN)      // 16384
#define QKVC (3*NC)     // 2304
#define QSCALE 0.18033688011112042f   // 0.125 * log2(e)

typedef _Float16 f16;
typedef _Float16 f16x8 __attribute__((ext_vector_type(8)));
typedef _Float16 f16x4 __attribute__((ext_vector_type(4)));
typedef __fp16 fp16x2 __attribute__((ext_vector_type(2)));   // cvt_pkrtz native type
typedef float f32x4 __attribute__((ext_vector_type(4)));

__device__ inline f16x8 as_f16x8(uint4 u){
  union { uint4 u; f16x8 h; } v; v.u = u; return v.h;
}

// async global->LDS, 16B per lane; lds ptr must be wave-uniform (lane l lands at +l*16B)
__device__ inline void gl_lds16(const f16* g, f16* l){
  __builtin_amdgcn_global_load_lds(
      (const __attribute__((address_space(1))) void*)g,
      (__attribute__((address_space(3))) void*)l, 16, 0, 0);
}

// ---------------- fp32 -> f16 convert ----------------
__global__ void cvt_f32_f16(const float* __restrict__ in, f16* __restrict__ out, int n4){
  int i = blockIdx.x*blockDim.x + threadIdx.x;
  if (i < n4){
    float4 v = ((const float4*)in)[i];
    f16x4 h; h[0]=(f16)v.x; h[1]=(f16)v.y; h[2]=(f16)v.z; h[3]=(f16)v.w;
    ((f16x4*)out)[i] = h;
  }
}

// ---------------- QKV GEMM: [16384,768] x [2304,768]^T, 128x128 tile ----------------
__launch_bounds__(256)
__global__ void gemm_qkv(const f16* __restrict__ X, const f16* __restrict__ W,
                         f16* __restrict__ Q, f16* __restrict__ K, f16* __restrict__ VT){
  __shared__ f16 sA[128*32];   // 8 KB, row-major [row][k], stride 32
  __shared__ f16 sB[128*32];
  const int R0 = blockIdx.y*128, C0 = blockIdx.x*128;
  const int t = threadIdx.x;
  const int w = t >> 6, l = t & 63, quad = l >> 4, lr = l & 15;
  const int wr = w >> 1, wc = w & 1;
  const int row0 = t >> 2, kc0 = (t & 3)*8;
  f32x4 acc[4][4] = {};
  for (int bk = 0; bk < NC; bk += 32){
#pragma unroll
    for (int r = 0; r < 2; r++){
      int row = r*64 + row0;
      gl_lds16(X + (size_t)(R0 + row)*NC + bk + kc0, sA + r*2048 + w*512);
      gl_lds16(W + (size_t)(C0 + row)*NC + bk + kc0, sB + r*2048 + w*512);
    }
    __syncthreads();
    f16x8 af[4], bf[4];
#pragma unroll
    for (int mt = 0; mt < 4; mt++)
      af[mt] = as_f16x8(*(const uint4*)(sA + (wr*64 + mt*16 + lr)*32 + quad*8));
#pragma unroll
    for (int nt = 0; nt < 4; nt++)
      bf[nt] = as_f16x8(*(const uint4*)(sB + (wc*64 + nt*16 + lr)*32 + quad*8));
#pragma unroll
    for (int mt = 0; mt < 4; mt++)
#pragma unroll
      for (int nt = 0; nt < 4; nt++)
        acc[mt][nt] = __builtin_amdgcn_mfma_f32_16x16x32_f16(af[mt], bf[nt], acc[mt][nt], 0, 0, 0);
    __syncthreads();
  }
  // scatter into Q / K / V^T. type uniform per block (128 | 768).
  const int type = C0 / NC;
#pragma unroll
  for (int nt = 0; nt < 4; nt++){
    int colg = C0 + wc*64 + nt*16 + lr;
    int rem  = colg - type*NC;
    int hh = rem >> 6, d = rem & 63;
#pragma unroll
    for (int mt = 0; mt < 4; mt++)
#pragma unroll
      for (int i = 0; i < 4; i++){
        int row = R0 + wr*64 + mt*16 + quad*4 + i;
        int bb = row >> 10, np = row & 1023;
        int bh = bb*NH + hh;
        float a = acc[mt][nt][i];
        if (type == 0)      Q[(bh << 16) + (np << 6) + d] = (f16)(a * QSCALE);
        else if (type == 1) K[(bh << 16) + (np << 6) + d] = (f16)a;
        else                VT[(bh << 16) + (d << 10) + np] = (f16)a;
      }
  }
}

// ---------------- Vsum: column sums of V per (b,h) ----------------
__global__ void vsum_kernel(const f16* __restrict__ VT, float* __restrict__ vsum){
  int bh = blockIdx.x;
  int t = threadIdx.x;
  int row = t >> 2, part = t & 3;
  const uint4* p = (const uint4*)(VT + ((size_t)bh << 16) + row*NN + part*256);
  float s = 0.f;
#pragma unroll
  for (int i = 0; i < 32; i++){
    f16x8 v = as_f16x8(p[i]);
#pragma unroll
    for (int j = 0; j < 8; j++) s += (float)v[j];
  }
  __shared__ float sR[64][4];
  sR[row][part] = s;
  __syncthreads();
  if (t < 64) vsum[bh*64 + t] = sR[t][0] + sR[t][1] + sR[t][2] + sR[t][3];
}

// ---------------- fused policy-softmax attention (no-max-subtract) ----------------
// Grid: 1536 blocks; decode bh = blk % 192 (XCD swizzle: same-bh blocks land on
// one XCD), qt = blk / 192. 256 thr = 4 independent waves (32 queries each).
// Q pre-scaled by 0.125*log2e -> e = exp2(acc). S computed in two 64-key halves
// (32 transient acc VGPRs). l via ones-MFMA. Epilogue restores exact reference
// eps semantics: out = (O + eps/N*E*Vsum)/(l + eps*E), E = exp2(rowmax).
#define PSTR 136   // f16 row stride: 272B, 16B-aligned
__launch_bounds__(256, 3)
__global__ void attn_kernel(const f16* __restrict__ Q, const f16* __restrict__ K,
                            const f16* __restrict__ VT, const float* __restrict__ policy,
                            const float* __restrict__ vsum, f16* __restrict__ O){
  __shared__ f16 sP[4][2][16][PSTR];   // 34816 B
  __shared__ float sPol[1024];         // 4096 B

  const int blk = blockIdx.x;
  const int bh = blk % (NB*NH);        // stride-192 => same XCD for all qt of a bh
  const int qt = blk / (NB*NH);
  const int b = bh / NH;
  const size_t base = (size_t)bh << 16;

  const int t = threadIdx.x;
  const int w = t >> 6, l = t & 63, quad = l >> 4, lr = l & 15;
  const int q0 = qt*128 + w*32;
  const int qrow = q0 + lr;
  const int h = bh - b*NH;

  *(float4*)&sPol[t*4] = *(const float4*)(policy + b*NN + t*4);

  // Q fragments (pre-scaled), contiguous 16B global reads
  f16x8 qf[2][2];
#pragma unroll
  for (int tq = 0; tq < 2; tq++)
#pragma unroll
    for (int hf = 0; hf < 2; hf++)
      qf[tq][hf] = as_f16x8(*(const uint4*)(Q + base + (size_t)(q0 + tq*16 + lr)*HD + hf*32 + quad*8));

  float vs[4];
#pragma unroll
  for (int nt = 0; nt < 4; nt++) vs[nt] = vsum[bh*64 + nt*16 + lr];

  f16x8 ones;
#pragma unroll
  for (int j = 0; j < 8; j++) ones[j] = (f16)1.0f;

  float m_run[2] = {-INFINITY, -INFINITY};
  f32x4 acc_l[2] = {};
  f32x4 o[2][4] = {};

  __syncthreads();   // sPol ready

  for (int c = 0; c < 8; c++){
    const int key0 = c*128;
    // ---- S^T chunk in two 64-key halves (32 transient acc VGPRs each)
#pragma unroll
    for (int half = 0; half < 2; half++){
      const int k0h = key0 + half*64;
      f32x4 accA[4], accB[4];
#pragma unroll
      for (int ct = 0; ct < 4; ct++){ accA[ct] = (f32x4){0,0,0,0}; accB[ct] = (f32x4){0,0,0,0}; }
#pragma unroll
      for (int ct = 0; ct < 4; ct++){
        const f16* kp = K + base + (size_t)(k0h + ct*16 + lr)*HD + quad*8;
        f16x8 k0 = as_f16x8(*(const uint4*)kp);
        f16x8 k1 = as_f16x8(*(const uint4*)(kp + 32));
        accA[ct] = __builtin_amdgcn_mfma_f32_16x16x32_f16(k0, qf[0][0], accA[ct], 0, 0, 0);
        accA[ct] = __builtin_amdgcn_mfma_f32_16x16x32_f16(k1, qf[0][1], accA[ct], 0, 0, 0);
        accB[ct] = __builtin_amdgcn_mfma_f32_16x16x32_f16(k0, qf[1][0], accB[ct], 0, 0, 0);
        accB[ct] = __builtin_amdgcn_mfma_f32_16x16x32_f16(k1, qf[1][1], accB[ct], 0, 0, 0);
      }
      float mA = m_run[0], mB = m_run[1];
      // diagonal keys of this block's queries live in chunk qt, half (w>>1) — wave-uniform
      if (c != qt || half != (w >> 1)){
#pragma unroll
        for (int ct = 0; ct < 4; ct++){
          int kb = half*64 + ct*16 + quad*4;
          float4 pol4 = *(const float4*)&sPol[key0 + kb];
          const float* p4 = (const float*)&pol4;
          mA = fmaxf(mA, fmaxf(fmaxf(accA[ct][0], accA[ct][1]), fmaxf(accA[ct][2], accA[ct][3])));
          mB = fmaxf(mB, fmaxf(fmaxf(accB[ct][0], accB[ct][1]), fmaxf(accB[ct][2], accB[ct][3])));
          union { f16x4 v; fp16x2 h[2]; } uA, uB;
          uA.h[0] = __builtin_amdgcn_cvt_pkrtz(exp2f(accA[ct][0])*p4[0], exp2f(accA[ct][1])*p4[1]);
          uA.h[1] = __builtin_amdgcn_cvt_pkrtz(exp2f(accA[ct][2])*p4[2], exp2f(accA[ct][3])*p4[3]);
          uB.h[0] = __builtin_amdgcn_cvt_pkrtz(exp2f(accB[ct][0])*p4[0], exp2f(accB[ct][1])*p4[1]);
          uB.h[1] = __builtin_amdgcn_cvt_pkrtz(exp2f(accB[ct][2])*p4[2], exp2f(accB[ct][3])*p4[3]);
          *(f16x4*)&sP[w][0][lr][kb] = uA.v;
          *(f16x4*)&sP[w][1][lr][kb] = uB.v;
        }
      } else {
#pragma unroll
        for (int ct = 0; ct < 4; ct++){
          int kb = half*64 + ct*16 + quad*4;
          float4 pol4 = *(const float4*)&sPol[key0 + kb];
          const float* p4 = (const float*)&pol4;
          float eA[4], eB[4];
#pragma unroll
          for (int i = 0; i < 4; i++){
            int kg = key0 + kb + i;
            float polA = (kg == qrow)      ? 1.0f : p4[i];
            float polB = (kg == qrow + 16) ? 1.0f : p4[i];
            mA = fmaxf(mA, accA[ct][i]); mB = fmaxf(mB, accB[ct][i]);
            eA[i] = exp2f(accA[ct][i]) * polA;
            eB[i] = exp2f(accB[ct][i]) * polB;
          }
          union { f16x4 v; fp16x2 h[2]; } uA, uB;
          uA.h[0] = __builtin_amdgcn_cvt_pkrtz(eA[0], eA[1]);
          uA.h[1] = __builtin_amdgcn_cvt_pkrtz(eA[2], eA[3]);
          uB.h[0] = __builtin_amdgcn_cvt_pkrtz(eB[0], eB[1]);
          uB.h[1] = __builtin_amdgcn_cvt_pkrtz(eB[2], eB[3]);
          *(f16x4*)&sP[w][0][lr][kb] = uA.v;
          *(f16x4*)&sP[w][1][lr][kb] = uB.v;
        }
      }
      m_run[0] = mA; m_run[1] = mB;
    }

    // ---- O += P V^T ; l += P * ones (both MFMA)
#pragma unroll
    for (int s8 = 0; s8 < 4; s8++){
      f16x8 pfA = as_f16x8(*(const uint4*)&sP[w][0][lr][s8*32 + quad*8]);
      f16x8 pfB = as_f16x8(*(const uint4*)&sP[w][1][lr][s8*32 + quad*8]);
      acc_l[0] = __builtin_amdgcn_mfma_f32_16x16x32_f16(pfA, ones, acc_l[0], 0, 0, 0);
      acc_l[1] = __builtin_amdgcn_mfma_f32_16x16x32_f16(pfB, ones, acc_l[1], 0, 0, 0);
#pragma unroll
      for (int nt = 0; nt < 4; nt++){
        f16x8 vf = as_f16x8(*(const uint4*)(VT + base + (size_t)(nt*16 + lr)*NN + key0 + s8*32 + quad*8));
        o[0][nt] = __builtin_amdgcn_mfma_f32_16x16x32_f16(pfA, vf, o[0][nt], 0, 0, 0);
        o[1][nt] = __builtin_amdgcn_mfma_f32_16x16x32_f16(pfB, vf, o[1][nt], 0, 0, 0);
      }
    }
  }

  // ---- epilogue: out = (O + eps/N * E * Vsum) / (l + eps * E)
#pragma unroll
  for (int tq = 0; tq < 2; tq++){
    float mq = m_run[tq];
    mq = fmaxf(mq, __shfl_xor(mq, 16));
    mq = fmaxf(mq, __shfl_xor(mq, 32));   // per-query (lr) global max, all lanes
#pragma unroll
    for (int i = 0; i < 4; i++){
      float mi = __shfl(mq, quad*4 + i);  // max for query row quad*4+i
      float E  = exp2f(mi);
      float li = acc_l[tq][i];            // row-sum for this query
      float inv = 1.0f / (li + 1e-6f*E);
      float ec  = (1e-6f/1024.0f)*E;
      int row = q0 + tq*16 + quad*4 + i;
      f16* op = O + (size_t)(b*NN + row)*NC + h*HD;
#pragma unroll
      for (int nt = 0; nt < 4; nt++)
        op[nt*16 + lr] = (f16)((o[tq][nt][i] + ec*vs[nt]) * inv);
    }
  }
}

// ---------------- proj GEMM: [16384,768] x [768,768]^T + bias -> fp32, 128x128 ----------------
__launch_bounds__(256)
__global__ void gemm_proj(const f16* __restrict__ A, const f16* __restrict__ W,
                          const float* __restrict__ bias, float* __restrict__ out){
  __shared__ f16 sA[128*32];
  __shared__ f16 sB[128*32];
  const int R0 = blockIdx.y*128, C0 = blockIdx.x*128;
  const int t = threadIdx.x;
  const int w = t >> 6, l = t & 63, quad = l >> 4, lr = l & 15;
  const int wr = w >> 1, wc = w & 1;
  const int row0 = t >> 2, kc0 = (t & 3)*8;
  f32x4 acc[4][4] = {};
  for (int bk = 0; bk < NC; bk += 32){
#pragma unroll
    for (int r = 0; r < 2; r++){
      int row = r*64 + row0;
      gl_lds16(A + (size_t)(R0 + row)*NC + bk + kc0, sA + r*2048 + w*512);
      gl_lds16(W + (size_t)(C0 + row)*NC + bk + kc0, sB + r*2048 + w*512);
    }
    __syncthreads();
    f16x8 af[4], bf[4];
#pragma unroll
    for (int mt = 0; mt < 4; mt++)
      af[mt] = as_f16x8(*(const uint4*)(sA + (wr*64 + mt*16 + lr)*32 + quad*8));
#pragma unroll
    for (int nt = 0; nt < 4; nt++)
      bf[nt] = as_f16x8(*(const uint4*)(sB + (wc*64 + nt*16 + lr)*32 + quad*8));
#pragma unroll
    for (int mt = 0; mt < 4; mt++)
#pragma unroll
      for (int nt = 0; nt < 4; nt++)
        acc[mt][nt] = __builtin_amdgcn_mfma_f32_16x16x32_f16(af[mt], bf[nt], acc[mt][nt], 0, 0, 0);
    __syncthreads();
  }
#pragma unroll
  for (int nt = 0; nt < 4; nt++){
    int colg = C0 + wc*64 + nt*16 + lr;
    float bv = bias[colg];
#pragma unroll
    for (int mt = 0; mt < 4; mt++)
#pragma unroll
      for (int i = 0; i < 4; i++){
        int row = R0 + wr*64 + mt*16 + quad*4 + i;
        out[(size_t)row*NC + colg] = acc[mt][nt][i] + bv;
      }
  }
}

extern "C" void kernel_launch(void* const* d_in, const int* in_sizes, int n_in,
                              void* d_out, int out_size, void* d_ws, size_t ws_size,
                              hipStream_t stream) {
  const float* x      = (const float*)d_in[0];
  const float* policy = (const float*)d_in[1];
  const float* w_qkv  = (const float*)d_in[2];
  const float* w_proj = (const float*)d_in[3];
  const float* b_proj = (const float*)d_in[4];
  float* out = (float*)d_out;

  f16* x_h     = (f16*)d_ws;
  f16* wqkv_h  = x_h + (size_t)NM*NC;
  f16* wproj_h = wqkv_h + (size_t)QKVC*NC;
  f16* q_h     = wproj_h + (size_t)NC*NC;
  f16* k_h     = q_h + (size_t)NM*NC;
  f16* vt_h    = k_h + (size_t)NM*NC;
  float* vsum_f = (float*)(vt_h + (size_t)NM*NC);
  f16* attn_h  = x_h;   // x dead after gemm_qkv -> reuse

  cvt_f32_f16<<<(NM*NC/4 + 255)/256, 256, 0, stream>>>(x, x_h, NM*NC/4);
  cvt_f32_f16<<<(QKVC*NC/4 + 255)/256, 256, 0, stream>>>(w_qkv, wqkv_h, QKVC*NC/4);
  cvt_f32_f16<<<(NC*NC/4 + 255)/256, 256, 0, stream>>>(w_proj, wproj_h, NC*NC/4);

  gemm_qkv<<<dim3(QKVC/128, NM/128), 256, 0, stream>>>(x_h, wqkv_h, q_h, k_h, vt_h);

  vsum_kernel<<<dim3(NB*NH), 256, 0, stream>>>(vt_h, vsum_f);

  attn_kernel<<<dim3(NB*NH*(NN/128)), 256, 0, stream>>>(q_h, k_h, vt_h, policy, vsum_f, attn_h);

  gemm_proj<<<dim3(NC/128, NM/128), 256, 0, stream>>>(attn_h, wproj_h, b_proj, out);
}